// Round 1
// baseline (964.885 us; speedup 1.0000x reference)
//
#include <hip/hip_runtime.h>

#define SVOL (64 * 64 * 64)  // 262144 spatial sites per (n, c)

// ---------------------------------------------------------------------------
// Phase 1: transpose vol [N=8][C=32][S=262144] -> volT [N][S][C] (channel-last)
// so that the random gather in phase 2 reads contiguous 128 B per corner.
// LDS-tiled: coalesced float4 reads along S, coalesced float4 writes along C*S.
// ---------------------------------------------------------------------------
__global__ __launch_bounds__(256) void transpose_kernel(
    const float* __restrict__ vol, float* __restrict__ volT) {
    __shared__ float tile[32][257];  // +1 pad breaks bank-conflict strides

    const int t = threadIdx.x;
    const int n = blockIdx.y;
    const long s0 = (long)blockIdx.x * 256;

    const float* src = vol + (long)n * 32 * SVOL + s0;
    const int sl = (t & 63) * 4;     // s offset within tile
    const int cb = t >> 6;           // 0..3
#pragma unroll
    for (int it = 0; it < 8; ++it) {
        const int c = it * 4 + cb;
        const float4 v = *(const float4*)(src + (long)c * SVOL + sl);
        tile[c][sl + 0] = v.x;
        tile[c][sl + 1] = v.y;
        tile[c][sl + 2] = v.z;
        tile[c][sl + 3] = v.w;
    }
    __syncthreads();

    float* dst = volT + ((long)n * SVOL + s0) * 32;
    const int c4 = (t & 7) * 4;
#pragma unroll
    for (int it = 0; it < 8; ++it) {
        const int sl2 = it * 32 + (t >> 3);
        float4 v;
        v.x = tile[c4 + 0][sl2];
        v.y = tile[c4 + 1][sl2];
        v.z = tile[c4 + 2][sl2];
        v.w = tile[c4 + 3][sl2];
        *(float4*)(dst + (long)sl2 * 32 + c4) = v;
    }
}

// ---------------------------------------------------------------------------
// Phase 2: one thread per output spatial point; computes all 32 channels.
// Each corner gather is 8 sequential float4 loads from one 128 B line
// (channel-last layout) -> full line utilization, L1-friendly.
// OOB corners handled by zeroed weights (reference: padding_mode='zeros').
// ---------------------------------------------------------------------------
__global__ __launch_bounds__(256) void gather_kernel(
    const float* __restrict__ grid, const float* __restrict__ volT,
    float* __restrict__ out) {
    const long gidx = (long)blockIdx.x * 256 + threadIdx.x;  // point id
    const int n = (int)(gidx >> 18);          // SVOL == 2^18
    const int s = (int)(gidx & (SVOL - 1));

    const float* g = grid + gidx * 3;
    const float x = g[0];
    const float y = g[1];
    const float z = g[2];

    // align_corners=True: [-1,1] -> [0, 63]
    const float ix = (x + 1.0f) * 0.5f * 63.0f;
    const float iy = (y + 1.0f) * 0.5f * 63.0f;
    const float iz = (z + 1.0f) * 0.5f * 63.0f;

    const float fx = floorf(ix), fy = floorf(iy), fz = floorf(iz);
    const int ix0 = (int)fx, iy0 = (int)fy, iz0 = (int)fz;
    const float tx = ix - fx, ty = iy - fy, tz = iz - fz;

    // per-axis weights with zero-padding mask folded in
    float wx[2], wy[2], wz[2];
    int xc[2], yc[2], zc[2];
    wx[0] = (ix0 >= 0 && ix0 < 64) ? (1.0f - tx) : 0.0f;
    wx[1] = (ix0 + 1 >= 0 && ix0 + 1 < 64) ? tx : 0.0f;
    wy[0] = (iy0 >= 0 && iy0 < 64) ? (1.0f - ty) : 0.0f;
    wy[1] = (iy0 + 1 >= 0 && iy0 + 1 < 64) ? ty : 0.0f;
    wz[0] = (iz0 >= 0 && iz0 < 64) ? (1.0f - tz) : 0.0f;
    wz[1] = (iz0 + 1 >= 0 && iz0 + 1 < 64) ? tz : 0.0f;
    xc[0] = min(max(ix0, 0), 63);
    xc[1] = min(max(ix0 + 1, 0), 63);
    yc[0] = min(max(iy0, 0), 63);
    yc[1] = min(max(iy0 + 1, 0), 63);
    zc[0] = min(max(iz0, 0), 63);
    zc[1] = min(max(iz0 + 1, 0), 63);

    const float* base = volT + ((long)n * SVOL) * 32;

    float4 acc[8];
#pragma unroll
    for (int j = 0; j < 8; ++j) acc[j] = make_float4(0.f, 0.f, 0.f, 0.f);

#pragma unroll
    for (int k = 0; k < 8; ++k) {
        const int kx = k & 1;
        const int ky = (k >> 1) & 1;
        const int kz = k >> 2;
        const float w = wz[kz] * wy[ky] * wx[kx];
        const long off = ((long)((zc[kz] * 64 + yc[ky]) * 64 + xc[kx])) * 32;
        const float4* cp = (const float4*)(base + off);
#pragma unroll
        for (int j = 0; j < 8; ++j) {
            const float4 v = cp[j];
            acc[j].x = fmaf(w, v.x, acc[j].x);
            acc[j].y = fmaf(w, v.y, acc[j].y);
            acc[j].z = fmaf(w, v.z, acc[j].z);
            acc[j].w = fmaf(w, v.w, acc[j].w);
        }
    }

    // out [N][C][S]: lane-consecutive s -> every channel store is coalesced
    float* op = out + (long)n * 32 * SVOL + s;
#pragma unroll
    for (int j = 0; j < 8; ++j) {
        op[(long)(4 * j + 0) * SVOL] = acc[j].x;
        op[(long)(4 * j + 1) * SVOL] = acc[j].y;
        op[(long)(4 * j + 2) * SVOL] = acc[j].z;
        op[(long)(4 * j + 3) * SVOL] = acc[j].w;
    }
}

// ---------------------------------------------------------------------------
// Fallback (only if workspace is too small to hold the transposed volume):
// direct gather from [N,C,D,H,W]. Correct but line-inefficient.
// ---------------------------------------------------------------------------
__global__ __launch_bounds__(256) void gather_direct_kernel(
    const float* __restrict__ grid, const float* __restrict__ vol,
    float* __restrict__ out) {
    const long gidx = (long)blockIdx.x * 256 + threadIdx.x;
    const int n = (int)(gidx >> 18);
    const int s = (int)(gidx & (SVOL - 1));

    const float* g = grid + gidx * 3;
    const float ix = (g[0] + 1.0f) * 0.5f * 63.0f;
    const float iy = (g[1] + 1.0f) * 0.5f * 63.0f;
    const float iz = (g[2] + 1.0f) * 0.5f * 63.0f;

    const float fx = floorf(ix), fy = floorf(iy), fz = floorf(iz);
    const int ix0 = (int)fx, iy0 = (int)fy, iz0 = (int)fz;
    const float tx = ix - fx, ty = iy - fy, tz = iz - fz;

    float wx[2], wy[2], wz[2];
    int xc[2], yc[2], zc[2];
    wx[0] = (ix0 >= 0 && ix0 < 64) ? (1.0f - tx) : 0.0f;
    wx[1] = (ix0 + 1 < 64) ? tx : 0.0f;
    wy[0] = (iy0 >= 0 && iy0 < 64) ? (1.0f - ty) : 0.0f;
    wy[1] = (iy0 + 1 < 64) ? ty : 0.0f;
    wz[0] = (iz0 >= 0 && iz0 < 64) ? (1.0f - tz) : 0.0f;
    wz[1] = (iz0 + 1 < 64) ? tz : 0.0f;
    xc[0] = min(max(ix0, 0), 63);
    xc[1] = min(max(ix0 + 1, 0), 63);
    yc[0] = min(max(iy0, 0), 63);
    yc[1] = min(max(iy0 + 1, 0), 63);
    zc[0] = min(max(iz0, 0), 63);
    zc[1] = min(max(iz0 + 1, 0), 63);

    long offk[8];
    float wk[8];
#pragma unroll
    for (int k = 0; k < 8; ++k) {
        const int kx = k & 1, ky = (k >> 1) & 1, kz = k >> 2;
        offk[k] = (long)(zc[kz] * 64 + yc[ky]) * 64 + xc[kx];
        wk[k] = wz[kz] * wy[ky] * wx[kx];
    }

    const float* base = vol + (long)n * 32 * SVOL;
    float* op = out + (long)n * 32 * SVOL + s;
    for (int c = 0; c < 32; ++c) {
        const float* bc = base + (long)c * SVOL;
        float a = 0.0f;
#pragma unroll
        for (int k = 0; k < 8; ++k) a = fmaf(wk[k], bc[offk[k]], a);
        op[(long)c * SVOL] = a;
    }
}

extern "C" void kernel_launch(void* const* d_in, const int* in_sizes, int n_in,
                              void* d_out, int out_size, void* d_ws, size_t ws_size,
                              hipStream_t stream) {
    const float* vol = (const float*)d_in[0];   // [8,32,64,64,64] fp32
    const float* grid = (const float*)d_in[1];  // [8,64,64,64,3] fp32
    float* out = (float*)d_out;                 // [8,32,64,64,64] fp32

    const size_t needed = (size_t)8 * SVOL * 32 * sizeof(float);  // 256 MiB
    const int npoints_blocks = (8 * SVOL) / 256;                  // 8192

    if (ws_size >= needed) {
        float* volT = (float*)d_ws;
        transpose_kernel<<<dim3(1024, 8), 256, 0, stream>>>(vol, volT);
        gather_kernel<<<npoints_blocks, 256, 0, stream>>>(grid, volT, out);
    } else {
        gather_direct_kernel<<<npoints_blocks, 256, 0, stream>>>(grid, vol, out);
    }
}

// Round 2
// 678.912 us; speedup vs baseline: 1.4212x; 1.4212x over previous
//
#include <hip/hip_runtime.h>

#define SVOL (64 * 64 * 64)  // 262144 spatial sites per (n, c)

typedef float vfloat4 __attribute__((ext_vector_type(4)));
typedef unsigned int vuint4 __attribute__((ext_vector_type(4)));
typedef unsigned short vushort4 __attribute__((ext_vector_type(4)));

__device__ __forceinline__ unsigned short f32_to_bf16_rne(float f) {
    unsigned int u = __float_as_uint(f);
    unsigned int r = u + 0x7FFFu + ((u >> 16) & 1u);  // round to nearest even
    return (unsigned short)(r >> 16);
}

// ---------------------------------------------------------------------------
// Phase 1: transpose+compress vol [N=8][C=32][S] fp32 -> volT [N][S][C] bf16.
// Channel-last so the random gather reads one contiguous 64 B per corner.
// vol is read once -> nontemporal loads (don't pollute L2/L3 for volT).
// ---------------------------------------------------------------------------
__global__ __launch_bounds__(256) void transpose_bf16_kernel(
    const float* __restrict__ vol, unsigned short* __restrict__ volT) {
    __shared__ float tile[32][257];  // +1 pad

    const int t = threadIdx.x;
    const int n = blockIdx.y;
    const long s0 = (long)blockIdx.x * 256;

    const float* src = vol + (long)n * 32 * SVOL + s0;
    const int sl = (t & 63) * 4;  // s offset within tile
    const int cb = t >> 6;        // 0..3
#pragma unroll
    for (int it = 0; it < 8; ++it) {
        const int c = it * 4 + cb;
        const vfloat4 v =
            __builtin_nontemporal_load((const vfloat4*)(src + (long)c * SVOL + sl));
        tile[c][sl + 0] = v.x;
        tile[c][sl + 1] = v.y;
        tile[c][sl + 2] = v.z;
        tile[c][sl + 3] = v.w;
    }
    __syncthreads();

    unsigned short* dst = volT + ((long)n * SVOL + s0) * 32;
    const int c4 = (t & 7) * 4;
#pragma unroll
    for (int it = 0; it < 8; ++it) {
        const int sl2 = it * 32 + (t >> 3);
        vushort4 v;
        v.x = f32_to_bf16_rne(tile[c4 + 0][sl2]);
        v.y = f32_to_bf16_rne(tile[c4 + 1][sl2]);
        v.z = f32_to_bf16_rne(tile[c4 + 2][sl2]);
        v.w = f32_to_bf16_rne(tile[c4 + 3][sl2]);
        *(vushort4*)(dst + (long)sl2 * 32 + c4) = v;  // cached: gather reuses
    }
}

// ---------------------------------------------------------------------------
// Phase 2: one thread per output point; all 32 channels. Each corner is one
// 64 B burst (4x uint4) of bf16. Out stores are nontemporal so the 256 MB
// output stream doesn't evict volT (128 MB, fully L3-resident).
// ---------------------------------------------------------------------------
__device__ __forceinline__ void fma_bf16pair(float& a0, float& a1,
                                             unsigned int u, float w) {
    const float lo = __uint_as_float(u << 16);
    const float hi = __uint_as_float(u & 0xFFFF0000u);
    a0 = fmaf(w, lo, a0);
    a1 = fmaf(w, hi, a1);
}

__global__ __launch_bounds__(256) void gather_bf16_kernel(
    const float* __restrict__ grid, const unsigned short* __restrict__ volT,
    float* __restrict__ out) {
    const long gidx = (long)blockIdx.x * 256 + threadIdx.x;
    const int n = (int)(gidx >> 18);  // SVOL == 2^18
    const int s = (int)(gidx & (SVOL - 1));

    const float x = __builtin_nontemporal_load(grid + gidx * 3 + 0);
    const float y = __builtin_nontemporal_load(grid + gidx * 3 + 1);
    const float z = __builtin_nontemporal_load(grid + gidx * 3 + 2);

    // align_corners=True: [-1,1] -> [0, 63]
    const float ix = (x + 1.0f) * 0.5f * 63.0f;
    const float iy = (y + 1.0f) * 0.5f * 63.0f;
    const float iz = (z + 1.0f) * 0.5f * 63.0f;

    const float fx = floorf(ix), fy = floorf(iy), fz = floorf(iz);
    const int ix0 = (int)fx, iy0 = (int)fy, iz0 = (int)fz;
    const float tx = ix - fx, ty = iy - fy, tz = iz - fz;

    float wx[2], wy[2], wz[2];
    int xc[2], yc[2], zc[2];
    wx[0] = (ix0 >= 0 && ix0 < 64) ? (1.0f - tx) : 0.0f;
    wx[1] = (ix0 + 1 >= 0 && ix0 + 1 < 64) ? tx : 0.0f;
    wy[0] = (iy0 >= 0 && iy0 < 64) ? (1.0f - ty) : 0.0f;
    wy[1] = (iy0 + 1 >= 0 && iy0 + 1 < 64) ? ty : 0.0f;
    wz[0] = (iz0 >= 0 && iz0 < 64) ? (1.0f - tz) : 0.0f;
    wz[1] = (iz0 + 1 >= 0 && iz0 + 1 < 64) ? tz : 0.0f;
    xc[0] = min(max(ix0, 0), 63);
    xc[1] = min(max(ix0 + 1, 0), 63);
    yc[0] = min(max(iy0, 0), 63);
    yc[1] = min(max(iy0 + 1, 0), 63);
    zc[0] = min(max(iz0, 0), 63);
    zc[1] = min(max(iz0 + 1, 0), 63);

    const vuint4* base = (const vuint4*)(volT + (long)n * SVOL * 32);

    float acc[32];
#pragma unroll
    for (int c = 0; c < 32; ++c) acc[c] = 0.0f;

#pragma unroll
    for (int k = 0; k < 8; ++k) {
        const int kx = k & 1;
        const int ky = (k >> 1) & 1;
        const int kz = k >> 2;
        const float w = wz[kz] * wy[ky] * wx[kx];
        const long site = (long)((zc[kz] * 64 + yc[ky]) * 64 + xc[kx]);
        const vuint4* cp = base + site * 4;  // 64 B = 32 bf16 channels
#pragma unroll
        for (int q = 0; q < 4; ++q) {
            const vuint4 v = cp[q];
            fma_bf16pair(acc[q * 8 + 0], acc[q * 8 + 1], v.x, w);
            fma_bf16pair(acc[q * 8 + 2], acc[q * 8 + 3], v.y, w);
            fma_bf16pair(acc[q * 8 + 4], acc[q * 8 + 5], v.z, w);
            fma_bf16pair(acc[q * 8 + 6], acc[q * 8 + 7], v.w, w);
        }
    }

    // out [N][C][S]: lane-consecutive s -> each channel store is coalesced.
    float* op = out + (long)n * 32 * SVOL + s;
#pragma unroll
    for (int c = 0; c < 32; ++c) {
        __builtin_nontemporal_store(acc[c], op + (long)c * SVOL);
    }
}

// ---------------------------------------------------------------------------
// Fallback (workspace too small): direct fp32 gather from [N,C,D,H,W].
// ---------------------------------------------------------------------------
__global__ __launch_bounds__(256) void gather_direct_kernel(
    const float* __restrict__ grid, const float* __restrict__ vol,
    float* __restrict__ out) {
    const long gidx = (long)blockIdx.x * 256 + threadIdx.x;
    const int n = (int)(gidx >> 18);
    const int s = (int)(gidx & (SVOL - 1));

    const float* g = grid + gidx * 3;
    const float ix = (g[0] + 1.0f) * 0.5f * 63.0f;
    const float iy = (g[1] + 1.0f) * 0.5f * 63.0f;
    const float iz = (g[2] + 1.0f) * 0.5f * 63.0f;

    const float fx = floorf(ix), fy = floorf(iy), fz = floorf(iz);
    const int ix0 = (int)fx, iy0 = (int)fy, iz0 = (int)fz;
    const float tx = ix - fx, ty = iy - fy, tz = iz - fz;

    float wx[2], wy[2], wz[2];
    int xc[2], yc[2], zc[2];
    wx[0] = (ix0 >= 0 && ix0 < 64) ? (1.0f - tx) : 0.0f;
    wx[1] = (ix0 + 1 < 64) ? tx : 0.0f;
    wy[0] = (iy0 >= 0 && iy0 < 64) ? (1.0f - ty) : 0.0f;
    wy[1] = (iy0 + 1 < 64) ? ty : 0.0f;
    wz[0] = (iz0 >= 0 && iz0 < 64) ? (1.0f - tz) : 0.0f;
    wz[1] = (iz0 + 1 < 64) ? tz : 0.0f;
    xc[0] = min(max(ix0, 0), 63);
    xc[1] = min(max(ix0 + 1, 0), 63);
    yc[0] = min(max(iy0, 0), 63);
    yc[1] = min(max(iy0 + 1, 0), 63);
    zc[0] = min(max(iz0, 0), 63);
    zc[1] = min(max(iz0 + 1, 0), 63);

    long offk[8];
    float wk[8];
#pragma unroll
    for (int k = 0; k < 8; ++k) {
        const int kx = k & 1, ky = (k >> 1) & 1, kz = k >> 2;
        offk[k] = (long)(zc[kz] * 64 + yc[ky]) * 64 + xc[kx];
        wk[k] = wz[kz] * wy[ky] * wx[kx];
    }

    const float* base = vol + (long)n * 32 * SVOL;
    float* op = out + (long)n * 32 * SVOL + s;
    for (int c = 0; c < 32; ++c) {
        const float* bc = base + (long)c * SVOL;
        float a = 0.0f;
#pragma unroll
        for (int k = 0; k < 8; ++k) a = fmaf(wk[k], bc[offk[k]], a);
        op[(long)c * SVOL] = a;
    }
}

extern "C" void kernel_launch(void* const* d_in, const int* in_sizes, int n_in,
                              void* d_out, int out_size, void* d_ws, size_t ws_size,
                              hipStream_t stream) {
    const float* vol = (const float*)d_in[0];   // [8,32,64,64,64] fp32
    const float* grid = (const float*)d_in[1];  // [8,64,64,64,3] fp32
    float* out = (float*)d_out;                 // [8,32,64,64,64] fp32

    const size_t needed = (size_t)8 * SVOL * 32 * sizeof(unsigned short);  // 128 MiB
    const int npoints_blocks = (8 * SVOL) / 256;                           // 8192

    if (ws_size >= needed) {
        unsigned short* volT = (unsigned short*)d_ws;
        transpose_bf16_kernel<<<dim3(1024, 8), 256, 0, stream>>>(vol, volT);
        gather_bf16_kernel<<<npoints_blocks, 256, 0, stream>>>(grid, volT, out);
    } else {
        gather_direct_kernel<<<npoints_blocks, 256, 0, stream>>>(grid, vol, out);
    }
}